// Round 6
// baseline (693.864 us; speedup 1.0000x reference)
//
#include <hip/hip_runtime.h>

typedef __bf16 bf16;
typedef __bf16 bf16x8 __attribute__((ext_vector_type(8)));
typedef __bf16 bf16x4 __attribute__((ext_vector_type(4)));
typedef float  f32x4  __attribute__((ext_vector_type(4)));

#define B_   2
#define S_   4096
#define HID_ 2048
#define H_   16
#define D_   128
#define C_   256
#define NC_  16
#define M_   (B_*S_)   // 8192 rows
#define K_   2048      // inner dim of both big GEMMs

typedef __attribute__((address_space(1))) const void gas_t;
typedef __attribute__((address_space(3))) void las_t;

// ---------------------------------------------------------------------------
// Fused convert: blocks [0,8192) do f32->bf16 of x (8 elems/thread);
// blocks [8192,28672) transpose-convert weights to bf16 [N][K]:
// rows 0..6143 = w_qkv cols, 6144..8191 = w_gate cols, 8192..10239 = w_out.
// ---------------------------------------------------------------------------
__global__ void cvt_kernel(const float* __restrict__ x,
                           const float* __restrict__ wqkv,
                           const float* __restrict__ wgate,
                           const float* __restrict__ wout,
                           bf16* __restrict__ xb, bf16* __restrict__ wT) {
    __shared__ float tile[32][33];
    int bid = blockIdx.x, tid = threadIdx.x;
    if (bid < 8192) {
        int idx = (bid * 256 + tid) * 8;
        float4 f0 = *(const float4*)(x + idx);
        float4 f1 = *(const float4*)(x + idx + 4);
        bf16x8 o;
        o[0] = (bf16)f0.x; o[1] = (bf16)f0.y; o[2] = (bf16)f0.z; o[3] = (bf16)f0.w;
        o[4] = (bf16)f1.x; o[5] = (bf16)f1.y; o[6] = (bf16)f1.z; o[7] = (bf16)f1.w;
        *(bf16x8*)(xb + idx) = o;
        return;
    }
    bid -= 8192;
    int k0 = (bid & 63) * 32, n0 = (bid >> 6) * 32;
    const float* src; int ld, col0;
    if (n0 < 6144)      { src = wqkv;  ld = 6144; col0 = n0; }
    else if (n0 < 8192) { src = wgate; ld = 2048; col0 = n0 - 6144; }
    else                { src = wout;  ld = 2048; col0 = n0 - 8192; }
    int tx = tid & 31, ty = tid >> 5;
#pragma unroll
    for (int i = 0; i < 4; i++) {
        int kk = ty + i * 8;
        tile[kk][tx] = src[(size_t)(k0 + kk) * ld + col0 + tx];
    }
    __syncthreads();
#pragma unroll
    for (int i = 0; i < 4; i++) {
        int nn = ty + i * 8;
        wT[(size_t)(n0 + nn) * K_ + k0 + tx] = (bf16)tile[tx][nn];
    }
}

// ---------------------------------------------------------------------------
// bf16 GEMM, C[M][N] = act( A[M][K] @ B[N][K]^T ).
// 256x256 tile, BK=64, 8 waves (2Mx4N), 512 threads - 8-phase schedule
// (T2 swizzle + T3/T4 counted-vmcnt phases + T5 setprio):
//   per iteration: 2 K-tiles (buf0, buf1), 4 phases each:
//     {ds_read subtile || stage half-tile prefetch} -> s_barrier ->
//     lgkmcnt(0) -> setprio(1) -> 16 MFMA -> setprio(0) -> s_barrier
//   vmcnt(6) only at phases 4 and 8 (3 half-tiles = 6 loads in flight).
// Output stores are NON-TEMPORAL: C is never re-read by this kernel, and
// letting the 128 MiB output stream allocate in L3 evicts the A/B panels
// (round-3 evidence: FETCH 197 MB vs 64 MB unique inputs).
// LDS: As/Bs[2bufs][2 halves][128x64] bf16 = 128 KiB, 8-slot XOR swizzle
// (physical 16B slot p of row r holds logical slot p ^ (r&7)); staged via
// inverse-swizzled GLOBAL source + linear global_load_lds dest (G21).
// MODE 0: N=8192, split output into q/k/v (silu) and gate (sigmoid), bf16.
// MODE 1: N=2048, plain f32 output to d_out.
// ---------------------------------------------------------------------------
#define DSRA(dst, buf, tb) do {                                              \
    const bf16* _p = &As[buf][wr][0];                                        \
    _Pragma("unroll")                                                        \
    for (int _t = 0; _t < 4; _t++) {                                         \
        const int _r = ((tb) + _t) * 16 + l15;                               \
        dst[_t][0] = *(const bf16x8*)(_p + _r * 64 + ps0);                   \
        dst[_t][1] = *(const bf16x8*)(_p + _r * 64 + ps1);                   \
    }                                                                        \
} while (0)

#define DSRB(dst, buf, tb) do {                                              \
    const bf16* _p = &Bs[buf][wch][0];                                       \
    _Pragma("unroll")                                                        \
    for (int _t = 0; _t < 2; _t++) {                                         \
        const int _r = bro + ((tb) + _t) * 16 + l15;                         \
        dst[_t][0] = *(const bf16x8*)(_p + _r * 64 + ps0);                   \
        dst[_t][1] = *(const bf16x8*)(_p + _r * 64 + ps1);                   \
    }                                                                        \
} while (0)

#define STAGE_A(buf, h, kt) do {                                             \
    const bf16* _s = Ag + (size_t)(h) * (128 * K_) + (kt) * 64;              \
    bf16* _d = &As[buf][h][srow * 64 + sslot * 8];                           \
    __builtin_amdgcn_global_load_lds((gas_t*)_s, (las_t*)_d, 16, 0, 0);      \
    __builtin_amdgcn_global_load_lds((gas_t*)(_s + (size_t)64 * K_),         \
                                     (las_t*)(_d + 4096), 16, 0, 0);         \
} while (0)

#define STAGE_B(buf, h, kt) do {                                             \
    const bf16* _s = Bg + (size_t)(h) * (128 * K_) + (kt) * 64;              \
    bf16* _d = &Bs[buf][h][srow * 64 + sslot * 8];                           \
    __builtin_amdgcn_global_load_lds((gas_t*)_s, (las_t*)_d, 16, 0, 0);      \
    __builtin_amdgcn_global_load_lds((gas_t*)(_s + (size_t)64 * K_),         \
                                     (las_t*)(_d + 4096), 16, 0, 0);         \
} while (0)

#define MM8(afr, bfr, ib, jb) do {                                           \
    _Pragma("unroll")                                                        \
    for (int _i = 0; _i < 4; _i++)                                           \
        _Pragma("unroll")                                                    \
        for (int _j = 0; _j < 2; _j++)                                       \
            _Pragma("unroll")                                                \
            for (int _k = 0; _k < 2; _k++)                                   \
                acc[(ib) + _i][(jb) + _j] =                                  \
                    __builtin_amdgcn_mfma_f32_16x16x32_bf16(                 \
                        afr[_i][_k], bfr[_j][_k],                            \
                        acc[(ib) + _i][(jb) + _j], 0, 0, 0);                 \
} while (0)

#define PTAIL(...) do {                                                      \
    __builtin_amdgcn_s_barrier();                                            \
    asm volatile("s_waitcnt lgkmcnt(0)" ::: "memory");                       \
    __builtin_amdgcn_s_setprio(1);                                           \
    __VA_ARGS__;                                                             \
    __builtin_amdgcn_s_setprio(0);                                           \
    __builtin_amdgcn_s_barrier();                                            \
} while (0)

#define VMC6 asm volatile("s_waitcnt vmcnt(6)" ::: "memory")
#define VMC0 asm volatile("s_waitcnt vmcnt(0)" ::: "memory")

template <int MODE>
__global__ __launch_bounds__(512, 2) void gemm_kernel(
        const bf16* __restrict__ A, const bf16* __restrict__ Bm,
        bf16* __restrict__ qo, bf16* __restrict__ ko,
        bf16* __restrict__ vo, bf16* __restrict__ go,
        float* __restrict__ out) {
    __shared__ __align__(16) bf16 As[2][2][128 * 64];
    __shared__ __align__(16) bf16 Bs[2][2][128 * 64];
    const int m0 = blockIdx.x * 256, n0 = blockIdx.y * 256;
    const int tid = threadIdx.x, lane = tid & 63, wid = tid >> 6;
    const int quad = lane >> 4, l15 = lane & 15;
    const int wr = wid >> 2, wc = wid & 3;
    const int wch = wc >> 1, bro = (wc & 1) * 64;
    const int srow = tid >> 3, sslot = tid & 7;
    const int lcol = (sslot ^ (srow & 7)) * 8;   // inverse-swizzled global col
    const int ps0 = ((quad)     ^ (l15 & 7)) * 8;
    const int ps1 = ((quad + 4) ^ (l15 & 7)) * 8;
    const bf16* Ag = A  + (size_t)(m0 + srow) * K_ + lcol;
    const bf16* Bg = Bm + (size_t)(n0 + srow) * K_ + lcol;

    f32x4 acc[8][4] = {};
    bf16x8 aLo[4][2], aHi[4][2], bLo[2][2], bHi[2][2];

    // prologue: tile0 A+B fully, tile1 B halves + A half0 (A1[1] staged at P1)
    STAGE_A(0, 0, 0); STAGE_A(0, 1, 0);
    STAGE_B(0, 0, 0); STAGE_B(0, 1, 0);
    STAGE_B(1, 0, 1); STAGE_B(1, 1, 1);
    STAGE_A(1, 0, 1);
    VMC6;   // tile0's 8 loads complete; 3 half-tiles in flight
    __builtin_amdgcn_s_barrier();

#pragma unroll 1
    for (int it = 0; it < 16; ++it) {
        const bool last = (it == 15);
        const int t2 = 2 * it + 2, t3 = 2 * it + 3;
        // P1: A-lo + B-lo of buf0; stage A1[1] (tile 2it+1, read at P5)
        DSRA(aLo, 0, 0); DSRB(bLo, 0, 0);
        STAGE_A(1, 1, 2 * it + 1);
        PTAIL(MM8(aLo, bLo, 0, 0));
        // P2: B-hi of buf0
        DSRB(bHi, 0, 2);
        PTAIL(MM8(aLo, bHi, 0, 2));
        // P3: A-hi of buf0; stage B-halves of buf0 for tile 2it+2
        DSRA(aHi, 0, 4);
        if (!last) { STAGE_B(0, 0, t2); STAGE_B(0, 1, t2); }
        PTAIL(MM8(aHi, bLo, 4, 0));
        // P4: stage A0[0]; counted wait -> buf1 (tile 2it+1) complete
        if (!last) STAGE_A(0, 0, t2);
        if (last) VMC0; else VMC6;
        PTAIL(MM8(aHi, bHi, 4, 2));
        // P5: A-lo + B-lo of buf1; stage A0[1]
        DSRA(aLo, 1, 0); DSRB(bLo, 1, 0);
        if (!last) STAGE_A(0, 1, t2);
        PTAIL(MM8(aLo, bLo, 0, 0));
        // P6: B-hi of buf1
        DSRB(bHi, 1, 2);
        PTAIL(MM8(aLo, bHi, 0, 2));
        // P7: A-hi of buf1; stage B-halves of buf1 for tile 2it+3
        DSRA(aHi, 1, 4);
        if (!last) { STAGE_B(1, 0, t3); STAGE_B(1, 1, t3); }
        PTAIL(MM8(aHi, bLo, 4, 0));
        // P8: stage A1[0]; counted wait -> buf0 (tile 2it+2) complete
        if (!last) STAGE_A(1, 0, t3);
        if (last) VMC0; else VMC6;
        PTAIL(MM8(aHi, bHi, 4, 2));
    }

    const int rb = m0 + wr * 128;
    if (MODE == 0) {
        bf16* outb = (n0 < 2048) ? qo : (n0 < 4096) ? ko : (n0 < 6144) ? vo : go;
        const bool silu = (n0 < 6144);
        const int cb = (n0 & 2047) + wc * 64;
#pragma unroll
        for (int ti = 0; ti < 8; ti++)
#pragma unroll
            for (int tj = 0; tj < 4; tj++)
#pragma unroll
                for (int r = 0; r < 4; r++) {
                    int row = rb + ti * 16 + quad * 4 + r;
                    int col = cb + tj * 16 + l15;
                    float xv = acc[ti][tj][r];
                    float sg = 1.f / (1.f + __expf(-xv));
                    float av = silu ? xv * sg : sg;
                    bf16 bv = (bf16)av;
                    __builtin_nontemporal_store(
                        *(unsigned short*)&bv,
                        (unsigned short*)(outb + (size_t)row * 2048 + col));
                }
    } else {
#pragma unroll
        for (int ti = 0; ti < 8; ti++)
#pragma unroll
            for (int tj = 0; tj < 4; tj++)
#pragma unroll
                for (int r = 0; r < 4; r++) {
                    int row = rb + ti * 16 + quad * 4 + r;
                    int col = n0 + wc * 64 + tj * 16 + l15;
                    __builtin_nontemporal_store(
                        acc[ti][tj][r], out + (size_t)row * 2048 + col);
                }
    }
}

#undef DSRA
#undef DSRB
#undef STAGE_A
#undef STAGE_B
#undef MM8
#undef PTAIL
#undef VMC6
#undef VMC0

// ---------------------------------------------------------------------------
// Transpose k and v per (b,h): [S][D] -> [D][S]   (bf16, LDS 64x64 tiles)
// grid (S/64, D/64, 2*32): z = arr*32 + bh.
// The k copy (arr==0) is pre-scaled by k_decay[j] = exp(-s*(255 - j%256)).
// ---------------------------------------------------------------------------
__global__ void transpose_kernel(const bf16* __restrict__ kin,
                                 const bf16* __restrict__ vin,
                                 const float* __restrict__ slopes,
                                 bf16* __restrict__ kT, bf16* __restrict__ vT) {
    __shared__ bf16 tile[64][65];
    int x0 = blockIdx.x * 64, d0 = blockIdx.y * 64;
    int z = blockIdx.z, arr = z >> 5, bh = z & 31, b = bh >> 4, h = bh & 15;
    const bf16* src = arr ? vin : kin;
    bf16* dst = arr ? vT : kT;
    int tx = threadIdx.x, ty = threadIdx.y;
    float fscale = 1.f;
    if (arr == 0)
        fscale = __expf(-slopes[h] * (float)(255 - ((x0 + tx) & 255)));
#pragma unroll
    for (int r = 0; r < 16; r++) {
        int lr = ty * 16 + r;
        tile[lr][tx] = src[(size_t)(b * S_ + x0 + lr) * 2048 + h * 128 + d0 + tx];
    }
    __syncthreads();
#pragma unroll
    for (int r = 0; r < 16; r++) {
        int lr = ty * 16 + r;
        dst[(size_t)(bh * 128 + d0 + lr) * S_ + x0 + tx] =
            (bf16)((float)tile[tx][lr] * fscale);
    }
}

// ---------------------------------------------------------------------------
// Pass A: per (chunk c, b, h) KV^T[e][d] = sum_j vT[e][j] * kT_scaled[d][j].
// M=N=128, K=256.  Pure load+MFMA (decay pre-folded into kT).
// ---------------------------------------------------------------------------
__global__ __launch_bounds__(256) void pass_a_kernel(
        const bf16* __restrict__ kT, const bf16* __restrict__ vT,
        bf16* __restrict__ KVT) {
    int c = blockIdx.x, bh = blockIdx.y;
    int tid = threadIdx.x, lane = tid & 63, wid = tid >> 6;
    int quad = lane >> 4, l15 = lane & 15;
    int e0 = (wid >> 1) * 64, d0 = (wid & 1) * 64;
    const bf16* vb = vT + (size_t)bh * 128 * S_ + c * 256;
    const bf16* kb = kT + (size_t)bh * 128 * S_ + c * 256;
    f32x4 acc[4][4] = {};
    for (int kbs = 0; kbs < 256; kbs += 32) {
        int j0 = kbs + quad * 8;
        bf16x8 af[4], bfr[4];
#pragma unroll
        for (int t = 0; t < 4; t++)
            af[t] = *(const bf16x8*)(vb + (size_t)(e0 + t * 16 + l15) * S_ + j0);
#pragma unroll
        for (int t = 0; t < 4; t++)
            bfr[t] = *(const bf16x8*)(kb + (size_t)(d0 + t * 16 + l15) * S_ + j0);
#pragma unroll
        for (int ti = 0; ti < 4; ti++)
#pragma unroll
            for (int tj = 0; tj < 4; tj++)
                acc[ti][tj] = __builtin_amdgcn_mfma_f32_16x16x32_bf16(
                    af[ti], bfr[tj], acc[ti][tj], 0, 0, 0);
    }
    size_t base = ((size_t)c * 32 + bh) * 16384;
#pragma unroll
    for (int ti = 0; ti < 4; ti++)
#pragma unroll
        for (int tj = 0; tj < 4; tj++)
#pragma unroll
            for (int r = 0; r < 4; r++) {
                int e = e0 + ti * 16 + quad * 4 + r, d = d0 + tj * 16 + l15;
                KVT[base + (size_t)e * 128 + d] = (bf16)acc[ti][tj][r];
            }
}

// ---------------------------------------------------------------------------
// Pass B: decayed prefix scan of KV^T over chunks; stT[c] = state BEFORE c.
// ---------------------------------------------------------------------------
__global__ void scan_kernel(const bf16* __restrict__ KVT,
                            const float* __restrict__ slopes,
                            bf16* __restrict__ stT) {
    int slice = blockIdx.x, bh = blockIdx.y;
    float s = slopes[bh & 15];
    float bd = __expf(-s * 256.f);
    size_t off = (size_t)slice * 1024 + threadIdx.x * 4;
    float kv0 = 0.f, kv1 = 0.f, kv2 = 0.f, kv3 = 0.f;
    for (int c = 0; c < 16; c++) {
        size_t idx = ((size_t)c * 32 + bh) * 16384 + off;
        bf16x4 st;
        st[0] = (bf16)kv0; st[1] = (bf16)kv1; st[2] = (bf16)kv2; st[3] = (bf16)kv3;
        *(bf16x4*)(stT + idx) = st;
        bf16x4 kvc = *(const bf16x4*)(KVT + idx);
        kv0 = bd * kv0 + (float)kvc[0];
        kv1 = bd * kv1 + (float)kvc[1];
        kv2 = bd * kv2 + (float)kvc[2];
        kv3 = bd * kv3 + (float)kvc[3];
    }
}

// ---------------------------------------------------------------------------
// Pass C (round-3 shape + wave-causal skip): wave w owns rows i0=w*64, so
// j-tiles jt>w are fully masked -> loop jt<=wid only (removes 37.5% of the
// intra-chunk MFMA work).  Inter-chunk q-decay applied as accumulator
// post-scale instead of per-K-step A-fragment repack.
// ---------------------------------------------------------------------------
__global__ __launch_bounds__(256) void pass_c_kernel(
        const bf16* __restrict__ q, const bf16* __restrict__ kk,
        const bf16* __restrict__ vT, const bf16* __restrict__ stT,
        const bf16* __restrict__ gate, const float* __restrict__ slopes,
        bf16* __restrict__ og) {
    __shared__ __align__(16) bf16 P[256 * 72];
    __shared__ float dtab[257];
    int c = blockIdx.x, bh = blockIdx.y, b = bh >> 4, h = bh & 15;
    int tid = threadIdx.x, lane = tid & 63, wid = tid >> 6;
    int quad = lane >> 4, l15 = lane & 15;
    int i0 = wid * 64;
    float s = slopes[h];
    dtab[tid] = __expf(-s * (float)tid);
    if (tid == 0) dtab[256] = __expf(-s * 256.f);
    __syncthreads();
    const bf16* qb = q  + ((size_t)(b * S_ + c * 256)) * 2048 + h * 128;
    const bf16* kb = kk + ((size_t)(b * S_ + c * 256)) * 2048 + h * 128;
    const bf16* vb = vT + (size_t)bh * 128 * S_ + c * 256;
    const bf16* st = stT + ((size_t)c * 32 + bh) * 16384;
    f32x4 acc[4][8] = {};

    // inter-chunk: q @ stateT rows, K=128 (decay applied after)
    for (int kbs = 0; kbs < 128; kbs += 32) {
        bf16x8 af[4];
#pragma unroll
        for (int t = 0; t < 4; t++)
            af[t] = *(const bf16x8*)(qb + (size_t)(i0 + t * 16 + l15) * 2048 + kbs + quad * 8);
#pragma unroll
        for (int te = 0; te < 8; te++) {
            bf16x8 bfr = *(const bf16x8*)(st + (size_t)(te * 16 + l15) * 128 + kbs + quad * 8);
#pragma unroll
            for (int t = 0; t < 4; t++)
                acc[t][te] = __builtin_amdgcn_mfma_f32_16x16x32_bf16(
                    af[t], bfr, acc[t][te], 0, 0, 0);
        }
    }
    // scale inter result by q_decay(row) = dtab[i+1]
#pragma unroll
    for (int t = 0; t < 4; t++) {
        float qd[4];
#pragma unroll
        for (int r = 0; r < 4; r++) qd[r] = dtab[i0 + t * 16 + quad * 4 + r + 1];
#pragma unroll
        for (int te = 0; te < 8; te++)
#pragma unroll
            for (int r = 0; r < 4; r++) acc[t][te][r] *= qd[r];
    }

    // intra-chunk: only causal j-tiles (jt <= wid)
    for (int jt = 0; jt <= wid; jt++) {
        f32x4 sacc[4][4] = {};
        for (int kbs = 0; kbs < 128; kbs += 32) {
            bf16x8 af[4], bkr[4];
#pragma unroll
            for (int t = 0; t < 4; t++)
                af[t] = *(const bf16x8*)(qb + (size_t)(i0 + t * 16 + l15) * 2048 + kbs + quad * 8);
#pragma unroll
            for (int t = 0; t < 4; t++)
                bkr[t] = *(const bf16x8*)(kb + (size_t)(jt * 64 + t * 16 + l15) * 2048 + kbs + quad * 8);
#pragma unroll
            for (int ti = 0; ti < 4; ti++)
#pragma unroll
                for (int tj = 0; tj < 4; tj++)
                    sacc[ti][tj] = __builtin_amdgcn_mfma_f32_16x16x32_bf16(
                        af[ti], bkr[tj], sacc[ti][tj], 0, 0, 0);
        }
        // causal decay, write P rows (wave-private)
#pragma unroll
        for (int ti = 0; ti < 4; ti++)
#pragma unroll
            for (int tj = 0; tj < 4; tj++)
#pragma unroll
                for (int r = 0; r < 4; r++) {
                    int i = i0 + ti * 16 + quad * 4 + r;
                    int j = jt * 64 + tj * 16 + l15;
                    int diff = i - j;
                    float pv = (diff >= 0) ? sacc[ti][tj][r] * dtab[diff] : 0.f;
                    P[i * 72 + tj * 16 + l15] = (bf16)pv;
                }
        // o += P @ vT rows, K=64
#pragma unroll
        for (int k2 = 0; k2 < 64; k2 += 32) {
            bf16x8 af[4];
#pragma unroll
            for (int t = 0; t < 4; t++)
                af[t] = *(const bf16x8*)&P[(i0 + t * 16 + l15) * 72 + k2 + quad * 8];
#pragma unroll
            for (int te = 0; te < 8; te++) {
                bf16x8 bfr = *(const bf16x8*)(vb + (size_t)(te * 16 + l15) * S_ + jt * 64 + k2 + quad * 8);
#pragma unroll
                for (int t = 0; t < 4; t++)
                    acc[t][te] = __builtin_amdgcn_mfma_f32_16x16x32_bf16(
                        af[t], bfr, acc[t][te], 0, 0, 0);
            }
        }
    }

    // epilogue: multiply gate, store bf16
    const bf16* gb = gate + ((size_t)(b * S_ + c * 256)) * 2048 + h * 128;
    bf16* ob = og + ((size_t)(b * S_ + c * 256)) * 2048 + h * 128;
#pragma unroll
    for (int ti = 0; ti < 4; ti++)
#pragma unroll
        for (int te = 0; te < 8; te++)
#pragma unroll
            for (int r = 0; r < 4; r++) {
                int i = i0 + ti * 16 + quad * 4 + r;
                int e = te * 16 + l15;
                float gv = (float)gb[(size_t)i * 2048 + e];
                ob[(size_t)i * 2048 + e] = (bf16)(acc[ti][te][r] * gv);
            }
}

// ---------------------------------------------------------------------------
// Workspace budget (d_ws): 200 MiB.  wT 40 + xb 32 + q/k/v/g 128.
// kT aliases xb (dead after GEMM1).  vT/KVT/stT live in d_out (64 MiB f32),
// all dead before GEMM2 overwrites d_out.
// ---------------------------------------------------------------------------
extern "C" void kernel_launch(void* const* d_in, const int* in_sizes, int n_in,
                              void* d_out, int out_size, void* d_ws, size_t ws_size,
                              hipStream_t stream) {
    const float* x      = (const float*)d_in[0];
    const float* wqkv   = (const float*)d_in[1];
    const float* wgate  = (const float*)d_in[2];
    const float* wout   = (const float*)d_in[3];
    const float* slopes = (const float*)d_in[4];
    float* out = (float*)d_out;

    bf16* wT   = (bf16*)d_ws;                       // [10240][2048]  40 MiB
    bf16* xb   = wT   + (size_t)10240 * 2048;       // [8192][2048]   32 MiB
    bf16* qb   = xb   + (size_t)8192 * 2048;        // 32 MiB
    bf16* kbuf = qb   + (size_t)8192 * 2048;        // 32 MiB
    bf16* vbuf = kbuf + (size_t)8192 * 2048;        // 32 MiB (reused: gated attn)
    bf16* gbuf = vbuf + (size_t)8192 * 2048;        // 32 MiB
    bf16* kT   = xb;                                // alias: xb dead after GEMM1
    bf16* vT   = (bf16*)d_out;                      // [32][128][4096] 32 MiB
    bf16* KVT  = vT + (size_t)32 * 128 * 4096;      // [16][32][128][128] 16 MiB
    bf16* stT  = KVT + (size_t)16 * 32 * 16384;     // 16 MiB  (total = 64 MiB)

    cvt_kernel<<<dim3(28672), dim3(256), 0, stream>>>(x, wqkv, wgate, wout, xb, wT);
    gemm_kernel<0><<<dim3(32, 32), dim3(512), 0, stream>>>(
        xb, wT, qb, kbuf, vbuf, gbuf, (float*)nullptr);
    transpose_kernel<<<dim3(64, 2, 64), dim3(64, 4), 0, stream>>>(
        kbuf, vbuf, slopes, kT, vT);
    pass_a_kernel<<<dim3(16, 32), dim3(256), 0, stream>>>(kT, vT, KVT);
    scan_kernel<<<dim3(16, 32), dim3(256), 0, stream>>>(KVT, slopes, stT);
    pass_c_kernel<<<dim3(16, 32), dim3(256), 0, stream>>>(
        qb, kbuf, vT, stT, gbuf, slopes, vbuf);
    gemm_kernel<1><<<dim3(32, 8), dim3(512), 0, stream>>>(
        vbuf, wT + (size_t)8192 * 2048, nullptr, nullptr, nullptr, nullptr, out);
}

// Round 8
// 606.826 us; speedup vs baseline: 1.1434x; 1.1434x over previous
//
#include <hip/hip_runtime.h>

typedef __bf16 bf16;
typedef __bf16 bf16x8 __attribute__((ext_vector_type(8)));
typedef __bf16 bf16x4 __attribute__((ext_vector_type(4)));
typedef float  f32x4  __attribute__((ext_vector_type(4)));

#define B_   2
#define S_   4096
#define HID_ 2048
#define H_   16
#define D_   128
#define C_   256
#define NC_  16
#define M_   (B_*S_)   // 8192 rows
#define K_   2048      // inner dim of both big GEMMs

typedef __attribute__((address_space(1))) const void gas_t;
typedef __attribute__((address_space(3))) void las_t;

// ---------------------------------------------------------------------------
// Fused convert: blocks [0,8192) do f32->bf16 of x (8 elems/thread);
// blocks [8192,28672) transpose-convert weights to bf16 [N][K]:
// rows 0..6143 = w_qkv cols, 6144..8191 = w_gate cols, 8192..10239 = w_out.
// ---------------------------------------------------------------------------
__global__ void cvt_kernel(const float* __restrict__ x,
                           const float* __restrict__ wqkv,
                           const float* __restrict__ wgate,
                           const float* __restrict__ wout,
                           bf16* __restrict__ xb, bf16* __restrict__ wT) {
    __shared__ float tile[32][33];
    int bid = blockIdx.x, tid = threadIdx.x;
    if (bid < 8192) {
        int idx = (bid * 256 + tid) * 8;
        float4 f0 = *(const float4*)(x + idx);
        float4 f1 = *(const float4*)(x + idx + 4);
        bf16x8 o;
        o[0] = (bf16)f0.x; o[1] = (bf16)f0.y; o[2] = (bf16)f0.z; o[3] = (bf16)f0.w;
        o[4] = (bf16)f1.x; o[5] = (bf16)f1.y; o[6] = (bf16)f1.z; o[7] = (bf16)f1.w;
        *(bf16x8*)(xb + idx) = o;
        return;
    }
    bid -= 8192;
    int k0 = (bid & 63) * 32, n0 = (bid >> 6) * 32;
    const float* src; int ld, col0;
    if (n0 < 6144)      { src = wqkv;  ld = 6144; col0 = n0; }
    else if (n0 < 8192) { src = wgate; ld = 2048; col0 = n0 - 6144; }
    else                { src = wout;  ld = 2048; col0 = n0 - 8192; }
    int tx = tid & 31, ty = tid >> 5;
#pragma unroll
    for (int i = 0; i < 4; i++) {
        int kk = ty + i * 8;
        tile[kk][tx] = src[(size_t)(k0 + kk) * ld + col0 + tx];
    }
    __syncthreads();
#pragma unroll
    for (int i = 0; i < 4; i++) {
        int nn = ty + i * 8;
        wT[(size_t)(n0 + nn) * K_ + k0 + tx] = (bf16)tile[tx][nn];
    }
}

// ---------------------------------------------------------------------------
// bf16 GEMM, C[M][N] = act( A[M][K] @ B[N][K]^T ).
// Round-3 proven 8-phase schedule (stage placement respects the buffer
// read/write hazards: B(t2)@P3+, A(t2)@P4+, B(t3)@P7+, A(t3)@P8/P1-wrap;
// vmcnt(6) at P4/P8 guarantees the consumed buffer is complete).
// NEW: transpose fusion in the MODE-0 epilogue.  After the K-loop the
// 128 KiB LDS is dead; k/v column-blocks bounce the 256x256 tile through
// LDS ([col][row], byte ^= (col&7)<<4 swizzle) and store it transposed:
//   v -> vT directly (row-major v store DROPPED - nothing consumed it),
//   k -> row-major k (pass_c) AND k_decay-scaled kT (pass_a).
// This eliminates the separate transpose kernel entirely.
// MODE 0: N=8192 -> q/k (silu, row-major), v (silu, transposed only),
//         gate (sigmoid, row-major).   MODE 1: N=2048, f32 out.
// ---------------------------------------------------------------------------
#define DSRA(dst, buf, tb) do {                                              \
    const bf16* _p = SMEM + ((buf) * 2 + wr) * 8192;                         \
    _Pragma("unroll")                                                        \
    for (int _t = 0; _t < 4; _t++) {                                         \
        const int _r = ((tb) + _t) * 16 + l15;                               \
        dst[_t][0] = *(const bf16x8*)(_p + _r * 64 + ps0);                   \
        dst[_t][1] = *(const bf16x8*)(_p + _r * 64 + ps1);                   \
    }                                                                        \
} while (0)

#define DSRB(dst, buf, tb) do {                                              \
    const bf16* _p = SMEM + 32768 + ((buf) * 2 + wch) * 8192;                \
    _Pragma("unroll")                                                        \
    for (int _t = 0; _t < 2; _t++) {                                         \
        const int _r = bro + ((tb) + _t) * 16 + l15;                         \
        dst[_t][0] = *(const bf16x8*)(_p + _r * 64 + ps0);                   \
        dst[_t][1] = *(const bf16x8*)(_p + _r * 64 + ps1);                   \
    }                                                                        \
} while (0)

#define STAGE_A(buf, h, kt) do {                                             \
    const bf16* _s = Ag + (size_t)(h) * (128 * K_) + (kt) * 64;              \
    bf16* _d = SMEM + ((buf) * 2 + (h)) * 8192 + srow * 64 + sslot * 8;      \
    __builtin_amdgcn_global_load_lds((gas_t*)_s, (las_t*)_d, 16, 0, 0);      \
    __builtin_amdgcn_global_load_lds((gas_t*)(_s + (size_t)64 * K_),         \
                                     (las_t*)(_d + 4096), 16, 0, 0);         \
} while (0)

#define STAGE_B(buf, h, kt) do {                                             \
    const bf16* _s = Bg + (size_t)(h) * (128 * K_) + (kt) * 64;              \
    bf16* _d = SMEM + 32768 + ((buf) * 2 + (h)) * 8192 + srow * 64 + sslot * 8; \
    __builtin_amdgcn_global_load_lds((gas_t*)_s, (las_t*)_d, 16, 0, 0);      \
    __builtin_amdgcn_global_load_lds((gas_t*)(_s + (size_t)64 * K_),         \
                                     (las_t*)(_d + 4096), 16, 0, 0);         \
} while (0)

#define MM8(afr, bfr, ib, jb) do {                                           \
    _Pragma("unroll")                                                        \
    for (int _i = 0; _i < 4; _i++)                                           \
        _Pragma("unroll")                                                    \
        for (int _j = 0; _j < 2; _j++)                                       \
            _Pragma("unroll")                                                \
            for (int _k = 0; _k < 2; _k++)                                   \
                acc[(ib) + _i][(jb) + _j] =                                  \
                    __builtin_amdgcn_mfma_f32_16x16x32_bf16(                 \
                        afr[_i][_k], bfr[_j][_k],                            \
                        acc[(ib) + _i][(jb) + _j], 0, 0, 0);                 \
} while (0)

#define PTAIL(...) do {                                                      \
    __builtin_amdgcn_s_barrier();                                            \
    asm volatile("s_waitcnt lgkmcnt(0)" ::: "memory");                       \
    __builtin_amdgcn_s_setprio(1);                                           \
    __VA_ARGS__;                                                             \
    __builtin_amdgcn_s_setprio(0);                                           \
    __builtin_amdgcn_s_barrier();                                            \
} while (0)

#define VMC6 asm volatile("s_waitcnt vmcnt(6)" ::: "memory")
#define VMC0 asm volatile("s_waitcnt vmcnt(0)" ::: "memory")

template <int MODE>
__global__ __launch_bounds__(512, 2) void gemm_kernel(
        const bf16* __restrict__ A, const bf16* __restrict__ Bm,
        bf16* __restrict__ qo, bf16* __restrict__ ko,
        bf16* __restrict__ go, bf16* __restrict__ vTd,
        bf16* __restrict__ kTd, const float* __restrict__ slopes,
        float* __restrict__ out) {
    __shared__ __align__(16) bf16 SMEM[65536];   // As [0,32768), Bs [32768,65536)
    const int m0 = blockIdx.x * 256, n0 = blockIdx.y * 256;
    const int tid = threadIdx.x, lane = tid & 63, wid = tid >> 6;
    const int quad = lane >> 4, l15 = lane & 15;
    const int wr = wid >> 2, wc = wid & 3;
    const int wch = wc >> 1, bro = (wc & 1) * 64;
    const int srow = tid >> 3, sslot = tid & 7;
    const int lcol = (sslot ^ (srow & 7)) * 8;   // inverse-swizzled global col
    const int ps0 = ((quad)     ^ (l15 & 7)) * 8;
    const int ps1 = ((quad + 4) ^ (l15 & 7)) * 8;
    const bf16* Ag = A  + (size_t)(m0 + srow) * K_ + lcol;
    const bf16* Bg = Bm + (size_t)(n0 + srow) * K_ + lcol;

    f32x4 acc[8][4] = {};
    bf16x8 aLo[4][2], aHi[4][2], bLo[2][2], bHi[2][2];

    // prologue: tile0 A+B fully, tile1 B halves + A half0 (A1[1] staged at P1)
    STAGE_A(0, 0, 0); STAGE_A(0, 1, 0);
    STAGE_B(0, 0, 0); STAGE_B(0, 1, 0);
    STAGE_B(1, 0, 1); STAGE_B(1, 1, 1);
    STAGE_A(1, 0, 1);
    VMC6;   // tile0's 8 loads complete; 3 half-tiles in flight
    __builtin_amdgcn_s_barrier();

#pragma unroll 1
    for (int it = 0; it < 16; ++it) {
        const bool last = (it == 15);
        const int t2 = 2 * it + 2, t3 = 2 * it + 3;
        // P1: A-lo + B-lo of buf0; stage A1[1] (tile 2it+1, read at P5/P7)
        DSRA(aLo, 0, 0); DSRB(bLo, 0, 0);
        STAGE_A(1, 1, 2 * it + 1);
        PTAIL(MM8(aLo, bLo, 0, 0));
        // P2: B-hi of buf0
        DSRB(bHi, 0, 2);
        PTAIL(MM8(aLo, bHi, 0, 2));
        // P3: A-hi of buf0; stage B-halves of buf0 for tile 2it+2
        DSRA(aHi, 0, 4);
        if (!last) { STAGE_B(0, 0, t2); STAGE_B(0, 1, t2); }
        PTAIL(MM8(aHi, bLo, 4, 0));
        // P4: stage A0[0]; counted wait -> buf1 (tile 2it+1) complete
        if (!last) STAGE_A(0, 0, t2);
        if (last) VMC0; else VMC6;
        PTAIL(MM8(aHi, bHi, 4, 2));
        // P5: A-lo + B-lo of buf1; stage A0[1]
        DSRA(aLo, 1, 0); DSRB(bLo, 1, 0);
        if (!last) STAGE_A(0, 1, t2);
        PTAIL(MM8(aLo, bLo, 0, 0));
        // P6: B-hi of buf1
        DSRB(bHi, 1, 2);
        PTAIL(MM8(aLo, bHi, 0, 2));
        // P7: A-hi of buf1; stage B-halves of buf1 for tile 2it+3
        DSRA(aHi, 1, 4);
        if (!last) { STAGE_B(1, 0, t3); STAGE_B(1, 1, t3); }
        PTAIL(MM8(aHi, bLo, 4, 0));
        // P8: stage A1[0]; counted wait -> buf0 (tile 2it+2) complete
        if (!last) STAGE_A(1, 0, t3);
        if (last) VMC0; else VMC6;
        PTAIL(MM8(aHi, bHi, 4, 2));
    }

    const int rb = m0 + wr * 128;
    if (MODE == 0) {
        const int kind = n0 >> 11;          // 0=q, 1=k, 2=v, 3=gate
        const int cb = n0 & 2047;
        // row-major stores for q, k, gate (v is transposed-only)
        if (kind != 2) {
            bf16* outb = (kind == 0) ? qo : (kind == 1) ? ko : go;
            const bool silu = (kind < 3);
#pragma unroll
            for (int ti = 0; ti < 8; ti++)
#pragma unroll
                for (int tj = 0; tj < 4; tj++)
#pragma unroll
                    for (int r = 0; r < 4; r++) {
                        int row = rb + ti * 16 + quad * 4 + r;
                        int col = cb + wc * 64 + tj * 16 + l15;
                        float xv = acc[ti][tj][r];
                        float sg = 1.f / (1.f + __expf(-xv));
                        float av = silu ? xv * sg : sg;
                        outb[(size_t)row * 2048 + col] = (bf16)av;
                    }
        }
        // transpose bounce for k and v through the (now dead) LDS
        if (kind == 1 || kind == 2) {
            // write [c][s] swizzled: byte = (c*512 + s*2) ^ ((c&7)<<4)
#pragma unroll
            for (int ti = 0; ti < 8; ti++)
#pragma unroll
                for (int tj = 0; tj < 4; tj++) {
                    int c = wc * 64 + tj * 16 + l15;
                    int s0 = wr * 128 + ti * 16 + quad * 4;
                    bf16x4 t4;
#pragma unroll
                    for (int r = 0; r < 4; r++) {
                        float xv = acc[ti][tj][r];
                        float sg = 1.f / (1.f + __expf(-xv));
                        t4[r] = (bf16)(xv * sg);   // silu (k and v both)
                    }
                    int byt = (c * 512 + s0 * 2) ^ ((c & 7) << 4);
                    *(bf16x4*)((char*)SMEM + byt) = t4;
                }
            __syncthreads();
            bf16* dstT = (kind == 2) ? vTd : kTd;
            const int bq = m0 >> 12, sbase = m0 & 4095, hb = cb >> 7;
            const int l = tid & 31, rg = tid >> 5;
#pragma unroll 1
            for (int p = 0; p < 16; ++p) {
                int c = p * 16 + rg;
                int byt = (c * 512 + l * 16) ^ ((c & 7) << 4);
                bf16x8 vv = *(const bf16x8*)((const char*)SMEM + byt);
                int h = hb + (c >> 7), d = c & 127;
                if (kind == 1) {        // k_decay: exp(-s*(255 - pos))
                    float sl = slopes[h];
                    float e = __expf(-sl * (float)(255 - l * 8));
                    float rr = __expf(sl);
#pragma unroll
                    for (int i = 0; i < 8; i++) {
                        vv[i] = (bf16)((float)vv[i] * e);
                        e *= rr;
                    }
                }
                *(bf16x8*)(dstT + ((size_t)(bq * 16 + h) * 128 + d) * (size_t)S_
                           + sbase + l * 8) = vv;
            }
        }
    } else {
#pragma unroll
        for (int ti = 0; ti < 8; ti++)
#pragma unroll
            for (int tj = 0; tj < 4; tj++)
#pragma unroll
                for (int r = 0; r < 4; r++) {
                    int row = rb + ti * 16 + quad * 4 + r;
                    int col = n0 + wc * 64 + tj * 16 + l15;
                    out[(size_t)row * 2048 + col] = acc[ti][tj][r];
                }
    }
}

#undef DSRA
#undef DSRB
#undef STAGE_A
#undef STAGE_B
#undef MM8
#undef PTAIL
#undef VMC6
#undef VMC0

// ---------------------------------------------------------------------------
// Pass A: per (chunk c, b, h) KV^T[e][d] = sum_j vT[e][j] * kT_scaled[d][j].
// M=N=128, K=256.  Pure load+MFMA (decay pre-folded into kT by GEMM0).
// ---------------------------------------------------------------------------
__global__ __launch_bounds__(256) void pass_a_kernel(
        const bf16* __restrict__ kT, const bf16* __restrict__ vT,
        bf16* __restrict__ KVT) {
    int c = blockIdx.x, bh = blockIdx.y;
    int tid = threadIdx.x, lane = tid & 63, wid = tid >> 6;
    int quad = lane >> 4, l15 = lane & 15;
    int e0 = (wid >> 1) * 64, d0 = (wid & 1) * 64;
    const bf16* vb = vT + (size_t)bh * 128 * S_ + c * 256;
    const bf16* kb = kT + (size_t)bh * 128 * S_ + c * 256;
    f32x4 acc[4][4] = {};
    for (int kbs = 0; kbs < 256; kbs += 32) {
        int j0 = kbs + quad * 8;
        bf16x8 af[4], bfr[4];
#pragma unroll
        for (int t = 0; t < 4; t++)
            af[t] = *(const bf16x8*)(vb + (size_t)(e0 + t * 16 + l15) * S_ + j0);
#pragma unroll
        for (int t = 0; t < 4; t++)
            bfr[t] = *(const bf16x8*)(kb + (size_t)(d0 + t * 16 + l15) * S_ + j0);
#pragma unroll
        for (int ti = 0; ti < 4; ti++)
#pragma unroll
            for (int tj = 0; tj < 4; tj++)
                acc[ti][tj] = __builtin_amdgcn_mfma_f32_16x16x32_bf16(
                    af[ti], bfr[tj], acc[ti][tj], 0, 0, 0);
    }
    size_t base = ((size_t)c * 32 + bh) * 16384;
#pragma unroll
    for (int ti = 0; ti < 4; ti++)
#pragma unroll
        for (int tj = 0; tj < 4; tj++)
#pragma unroll
            for (int r = 0; r < 4; r++) {
                int e = e0 + ti * 16 + quad * 4 + r, d = d0 + tj * 16 + l15;
                KVT[base + (size_t)e * 128 + d] = (bf16)acc[ti][tj][r];
            }
}

// ---------------------------------------------------------------------------
// Pass B: decayed prefix scan of KV^T over chunks; stT[c] = state BEFORE c.
// ---------------------------------------------------------------------------
__global__ void scan_kernel(const bf16* __restrict__ KVT,
                            const float* __restrict__ slopes,
                            bf16* __restrict__ stT) {
    int slice = blockIdx.x, bh = blockIdx.y;
    float s = slopes[bh & 15];
    float bd = __expf(-s * 256.f);
    size_t off = (size_t)slice * 1024 + threadIdx.x * 4;
    float kv0 = 0.f, kv1 = 0.f, kv2 = 0.f, kv3 = 0.f;
    for (int c = 0; c < 16; c++) {
        size_t idx = ((size_t)c * 32 + bh) * 16384 + off;
        bf16x4 st;
        st[0] = (bf16)kv0; st[1] = (bf16)kv1; st[2] = (bf16)kv2; st[3] = (bf16)kv3;
        *(bf16x4*)(stT + idx) = st;
        bf16x4 kvc = *(const bf16x4*)(KVT + idx);
        kv0 = bd * kv0 + (float)kvc[0];
        kv1 = bd * kv1 + (float)kvc[1];
        kv2 = bd * kv2 + (float)kvc[2];
        kv3 = bd * kv3 + (float)kvc[3];
    }
}

// ---------------------------------------------------------------------------
// Pass C (round-3 shape + wave-causal skip): wave w owns rows i0=w*64, so
// j-tiles jt>w are fully masked -> loop jt<=wid only.  Inter-chunk q-decay
// applied as accumulator post-scale.
// ---------------------------------------------------------------------------
__global__ __launch_bounds__(256) void pass_c_kernel(
        const bf16* __restrict__ q, const bf16* __restrict__ kk,
        const bf16* __restrict__ vT, const bf16* __restrict__ stT,
        const bf16* __restrict__ gate, const float* __restrict__ slopes,
        bf16* __restrict__ og) {
    __shared__ __align__(16) bf16 P[256 * 72];
    __shared__ float dtab[257];
    int c = blockIdx.x, bh = blockIdx.y, b = bh >> 4, h = bh & 15;
    int tid = threadIdx.x, lane = tid & 63, wid = tid >> 6;
    int quad = lane >> 4, l15 = lane & 15;
    int i0 = wid * 64;
    float s = slopes[h];
    dtab[tid] = __expf(-s * (float)tid);
    if (tid == 0) dtab[256] = __expf(-s * 256.f);
    __syncthreads();
    const bf16* qb = q  + ((size_t)(b * S_ + c * 256)) * 2048 + h * 128;
    const bf16* kb = kk + ((size_t)(b * S_ + c * 256)) * 2048 + h * 128;
    const bf16* vb = vT + (size_t)bh * 128 * S_ + c * 256;
    const bf16* st = stT + ((size_t)c * 32 + bh) * 16384;
    f32x4 acc[4][8] = {};

    // inter-chunk: q @ stateT rows, K=128 (decay applied after)
    for (int kbs = 0; kbs < 128; kbs += 32) {
        bf16x8 af[4];
#pragma unroll
        for (int t = 0; t < 4; t++)
            af[t] = *(const bf16x8*)(qb + (size_t)(i0 + t * 16 + l15) * 2048 + kbs + quad * 8);
#pragma unroll
        for (int te = 0; te < 8; te++) {
            bf16x8 bfr = *(const bf16x8*)(st + (size_t)(te * 16 + l15) * 128 + kbs + quad * 8);
#pragma unroll
            for (int t = 0; t < 4; t++)
                acc[t][te] = __builtin_amdgcn_mfma_f32_16x16x32_bf16(
                    af[t], bfr, acc[t][te], 0, 0, 0);
        }
    }
    // scale inter result by q_decay(row) = dtab[i+1]
#pragma unroll
    for (int t = 0; t < 4; t++) {
        float qd[4];
#pragma unroll
        for (int r = 0; r < 4; r++) qd[r] = dtab[i0 + t * 16 + quad * 4 + r + 1];
#pragma unroll
        for (int te = 0; te < 8; te++)
#pragma unroll
            for (int r = 0; r < 4; r++) acc[t][te][r] *= qd[r];
    }

    // intra-chunk: only causal j-tiles (jt <= wid)
    for (int jt = 0; jt <= wid; jt++) {
        f32x4 sacc[4][4] = {};
        for (int kbs = 0; kbs < 128; kbs += 32) {
            bf16x8 af[4], bkr[4];
#pragma unroll
            for (int t = 0; t < 4; t++)
                af[t] = *(const bf16x8*)(qb + (size_t)(i0 + t * 16 + l15) * 2048 + kbs + quad * 8);
#pragma unroll
            for (int t = 0; t < 4; t++)
                bkr[t] = *(const bf16x8*)(kb + (size_t)(jt * 64 + t * 16 + l15) * 2048 + kbs + quad * 8);
#pragma unroll
            for (int ti = 0; ti < 4; ti++)
#pragma unroll
                for (int tj = 0; tj < 4; tj++)
                    sacc[ti][tj] = __builtin_amdgcn_mfma_f32_16x16x32_bf16(
                        af[ti], bkr[tj], sacc[ti][tj], 0, 0, 0);
        }
        // causal decay, write P rows (wave-private)
#pragma unroll
        for (int ti = 0; ti < 4; ti++)
#pragma unroll
            for (int tj = 0; tj < 4; tj++)
#pragma unroll
                for (int r = 0; r < 4; r++) {
                    int i = i0 + ti * 16 + quad * 4 + r;
                    int j = jt * 64 + tj * 16 + l15;
                    int diff = i - j;
                    float pv = (diff >= 0) ? sacc[ti][tj][r] * dtab[diff] : 0.f;
                    P[i * 72 + tj * 16 + l15] = (bf16)pv;
                }
        // o += P @ vT rows, K=64
#pragma unroll
        for (int k2 = 0; k2 < 64; k2 += 32) {
            bf16x8 af[4];
#pragma unroll
            for (int t = 0; t < 4; t++)
                af[t] = *(const bf16x8*)&P[(i0 + t * 16 + l15) * 72 + k2 + quad * 8];
#pragma unroll
            for (int te = 0; te < 8; te++) {
                bf16x8 bfr = *(const bf16x8*)(vb + (size_t)(te * 16 + l15) * S_ + jt * 64 + k2 + quad * 8);
#pragma unroll
                for (int t = 0; t < 4; t++)
                    acc[t][te] = __builtin_amdgcn_mfma_f32_16x16x32_bf16(
                        af[t], bfr, acc[t][te], 0, 0, 0);
            }
        }
    }

    // epilogue: multiply gate, store bf16
    const bf16* gb = gate + ((size_t)(b * S_ + c * 256)) * 2048 + h * 128;
    bf16* ob = og + ((size_t)(b * S_ + c * 256)) * 2048 + h * 128;
#pragma unroll
    for (int ti = 0; ti < 4; ti++)
#pragma unroll
        for (int te = 0; te < 8; te++)
#pragma unroll
            for (int r = 0; r < 4; r++) {
                int i = i0 + ti * 16 + quad * 4 + r;
                int e = te * 16 + l15;
                float gv = (float)gb[(size_t)i * 2048 + e];
                ob[(size_t)i * 2048 + e] = (bf16)(acc[ti][te][r] * gv);
            }
}

// ---------------------------------------------------------------------------
// Workspace (d_ws, 200 MiB): wT 40 + xb 32 + qb 32 + kbuf 32 + kT/og 32 +
// gbuf 32.  The kT/og slot: GEMM0 writes scaled-transposed kT there (v's
// old row-major slot - v is now transposed-only); kT is dead after pass_a,
// then pass_c reuses the slot as its gated-attn output (GEMM1 input).
// vT/KVT/stT live in d_out (64 MiB f32), all dead before GEMM2 overwrites.
// ---------------------------------------------------------------------------
extern "C" void kernel_launch(void* const* d_in, const int* in_sizes, int n_in,
                              void* d_out, int out_size, void* d_ws, size_t ws_size,
                              hipStream_t stream) {
    const float* x      = (const float*)d_in[0];
    const float* wqkv   = (const float*)d_in[1];
    const float* wgate  = (const float*)d_in[2];
    const float* wout   = (const float*)d_in[3];
    const float* slopes = (const float*)d_in[4];
    float* out = (float*)d_out;

    bf16* wT   = (bf16*)d_ws;                       // [10240][2048]  40 MiB
    bf16* xb   = wT   + (size_t)10240 * 2048;       // [8192][2048]   32 MiB
    bf16* qb   = xb   + (size_t)8192 * 2048;        // 32 MiB
    bf16* kbuf = qb   + (size_t)8192 * 2048;        // 32 MiB (row-major k)
    bf16* kTn  = kbuf + (size_t)8192 * 2048;        // 32 MiB kT, then og
    bf16* gbuf = kTn  + (size_t)8192 * 2048;        // 32 MiB
    bf16* ogb  = kTn;                               // alias: kT dead by pass_c
    bf16* vT   = (bf16*)d_out;                      // [32][128][4096] 32 MiB
    bf16* KVT  = vT + (size_t)32 * 128 * 4096;      // [16][32][128][128] 16 MiB
    bf16* stT  = KVT + (size_t)16 * 32 * 16384;     // 16 MiB  (total = 64 MiB)

    cvt_kernel<<<dim3(28672), dim3(256), 0, stream>>>(x, wqkv, wgate, wout, xb, wT);
    gemm_kernel<0><<<dim3(32, 32), dim3(512), 0, stream>>>(
        xb, wT, qb, kbuf, gbuf, vT, kTn, slopes, (float*)nullptr);
    pass_a_kernel<<<dim3(16, 32), dim3(256), 0, stream>>>(kTn, vT, KVT);
    scan_kernel<<<dim3(16, 32), dim3(256), 0, stream>>>(KVT, slopes, stT);
    pass_c_kernel<<<dim3(16, 32), dim3(256), 0, stream>>>(
        qb, kbuf, vT, stT, gbuf, slopes, ogb);
    gemm_kernel<1><<<dim3(32, 8), dim3(512), 0, stream>>>(
        ogb, wT + (size_t)8192 * 2048, nullptr, nullptr, nullptr, nullptr,
        nullptr, nullptr, out);
}